// Round 1
// baseline (61.187 us; speedup 1.0000x reference)
//
#include <hip/hip_runtime.h>
#include <math.h>

#define BB 4

__device__ __forceinline__ float eluf(float v) {
  return v > 0.f ? v : __expf(v) - 1.f;
}

// Precompute reduced weights for the separable DI / DD pickers:
// wredT[sel][K*64+h] = sum_I wm[h,I,K] - sum_J wm[h,K,J]
__global__ void wred_kernel(const float* __restrict__ wm_di,
                            const float* __restrict__ wm_dd,
                            float* __restrict__ wredT) {
  int t = blockIdx.x * blockDim.x + threadIdx.x;  // 0..8191
  int sel = t >> 12;
  int idx = t & 4095;
  int h = idx >> 6, K = idx & 63;
  const float* w = (sel ? wm_dd : wm_di) + h * 4096;
  float cs = 0.f, rs = 0.f;
#pragma unroll 8
  for (int I = 0; I < 64; ++I) cs += w[I * 64 + K];
#pragma unroll 8
  for (int J = 0; J < 64; ++J) rs += w[K * 64 + J];
  wredT[sel * 4096 + K * 64 + h] = cs - rs;
}

__global__ __launch_bounds__(256) void fused_kernel(
    const float* __restrict__ x,
    const float* __restrict__ wm_ndi,
    const float* __restrict__ b_di, const float* __restrict__ b_ndi,
    const float* __restrict__ b_dd,
    const float* __restrict__ fcw_di, const float* __restrict__ fcb_di,
    const float* __restrict__ fcw_ndi, const float* __restrict__ fcb_ndi,
    const float* __restrict__ fcw_dd, const float* __restrict__ fcb_dd,
    const float* __restrict__ fc1_w, const float* __restrict__ fc1_b,
    const float* __restrict__ fc2_w, const float* __restrict__ fc2_b,
    const float* __restrict__ wredT,
    float* __restrict__ out) {
  __shared__ float xs[BB][256];
  __shared__ float sms[BB][256];
  __shared__ float dif[BB][256];
  __shared__ float pxs[BB][64];
  __shared__ float pds[BB][64];
  __shared__ float pndi[BB][4096];
  __shared__ float hh[3][BB][64];   // elu'd head activations per picker
  __shared__ float emb[BB][144];
  __shared__ float f1v[BB][48];

  const int t = threadIdx.x;
  const int b0 = blockIdx.x * BB;

  // ---- load x rows ----
#pragma unroll
  for (int r = 0; r < BB; ++r) xs[r][t] = x[(b0 + r) * 256 + t];
  __syncthreads();

  // ---- smooth: window 5, edge padding == index clamping ----
  const int m2 = max(t - 2, 0), m1 = max(t - 1, 0);
  const int q1 = min(t + 1, 255), q2 = min(t + 2, 255);
#pragma unroll
  for (int r = 0; r < BB; ++r)
    sms[r][t] = 0.2f * (xs[r][m2] + xs[r][m1] + xs[r][t] + xs[r][q1] + xs[r][q2]);
  __syncthreads();

  // ---- diff (prepend x[:,0]) ----
#pragma unroll
  for (int r = 0; r < BB; ++r)
    dif[r][t] = (t == 0) ? (sms[r][0] - xs[r][0]) : (sms[r][t] - sms[r][t - 1]);
  __syncthreads();

  // ---- 4-wide pooled x and pooled diff ----
  if (t < 64) {
#pragma unroll
    for (int r = 0; r < BB; ++r) {
      pxs[r][t] = 0.25f * (xs[r][4 * t] + xs[r][4 * t + 1] + xs[r][4 * t + 2] + xs[r][4 * t + 3]);
      pds[r][t] = 0.25f * (dif[r][4 * t] + dif[r][4 * t + 1] + dif[r][4 * t + 2] + dif[r][4 * t + 3]);
    }
  }
  // no barrier needed here: pndi phase only reads xs; pxs/pds consumed after later barriers

  // ---- pooled NDI: p[I,J] = 1/16 sum_{4x4} (xj-xi)/(xj+xi+1e-5) ----
  for (int cc = t; cc < BB * 4096; cc += 256) {
    const int r = cc >> 12;
    const int ij = cc & 4095;
    const int I = ij >> 6, J = ij & 63;
    const float4 xiv = *(const float4*)&xs[r][I << 2];
    const float4 xjv = *(const float4*)&xs[r][J << 2];
    const float xi_a[4] = {xiv.x, xiv.y, xiv.z, xiv.w};
    const float xj_a[4] = {xjv.x, xjv.y, xjv.z, xjv.w};
    float s = 0.f;
#pragma unroll
    for (int a = 0; a < 4; ++a) {
#pragma unroll
      for (int c = 0; c < 4; ++c) {
        const float num = xj_a[c] - xi_a[a];
        const float den = xj_a[c] + xi_a[a] + 1e-5f;
        s += num * __builtin_amdgcn_rcpf(den);
      }
    }
    pndi[r][ij] = s * 0.0625f;
  }
  __syncthreads();

  // ---- NDI einsum: each wave owns 16 heads; 64 lanes split K=4096 (as 1024 float4) ----
  {
    const int wave = t >> 6, lane = t & 63;
    for (int hi = 0; hi < 16; ++hi) {
      const int h = wave * 16 + hi;
      const float4* __restrict__ w4 = (const float4*)wm_ndi + h * 1024;
      float a0 = 0.f, a1 = 0.f, a2 = 0.f, a3 = 0.f;
#pragma unroll 4
      for (int k = 0; k < 16; ++k) {
        const int e = k * 64 + lane;
        const float4 wv = w4[e];
        const float4 p0 = *(const float4*)&pndi[0][e << 2];
        const float4 p1 = *(const float4*)&pndi[1][e << 2];
        const float4 p2 = *(const float4*)&pndi[2][e << 2];
        const float4 p3 = *(const float4*)&pndi[3][e << 2];
        a0 += wv.x * p0.x + wv.y * p0.y + wv.z * p0.z + wv.w * p0.w;
        a1 += wv.x * p1.x + wv.y * p1.y + wv.z * p1.z + wv.w * p1.w;
        a2 += wv.x * p2.x + wv.y * p2.y + wv.z * p2.z + wv.w * p2.w;
        a3 += wv.x * p3.x + wv.y * p3.y + wv.z * p3.z + wv.w * p3.w;
      }
#pragma unroll
      for (int off = 32; off; off >>= 1) {
        a0 += __shfl_xor(a0, off, 64);
        a1 += __shfl_xor(a1, off, 64);
        a2 += __shfl_xor(a2, off, 64);
        a3 += __shfl_xor(a3, off, 64);
      }
      if (lane == 0) {
        const float bb = b_ndi[h];
        hh[1][0][h] = eluf(a0 + bb);
        hh[1][1][h] = eluf(a1 + bb);
        hh[1][2][h] = eluf(a2 + bb);
        hh[1][3][h] = eluf(a3 + bb);
      }
    }
  }
  __syncthreads();

  // ---- DI / DD head projections via reduced weights (separable pooling) ----
  {
    const int r = t >> 6, h = t & 63;
    float adi = b_di[h], add_ = b_dd[h];
#pragma unroll 8
    for (int K = 0; K < 64; ++K) {
      adi  += pxs[r][K] * wredT[K * 64 + h];
      add_ += pds[r][K] * wredT[4096 + K * 64 + h];
    }
    hh[0][r][h] = eluf(adi);
    hh[2][r][h] = eluf(add_);
  }
  __syncthreads();

  // ---- per-picker fc: HEAD(64) -> EMB(48), writes concatenated emb[144] ----
  for (int idx = t; idx < BB * 144; idx += 256) {
    const int r = idx / 144;
    const int k = idx - r * 144;
    const int pick = k / 48;
    const int e = k - pick * 48;
    const float* __restrict__ fw = (pick == 0) ? fcw_di : (pick == 1) ? fcw_ndi : fcw_dd;
    const float* __restrict__ fb = (pick == 0) ? fcb_di : (pick == 1) ? fcb_ndi : fcb_dd;
    float a = fb[e];
#pragma unroll 8
    for (int hq = 0; hq < 64; ++hq) a += hh[pick][r][hq] * fw[e * 64 + hq];
    emb[r][k] = eluf(a);
  }
  __syncthreads();

  // ---- fc1: 144 -> 48, elu ----
  if (t < BB * 48) {
    const int r = t / 48, o = t - (t / 48) * 48;
    float a = fc1_b[o];
#pragma unroll 8
    for (int k = 0; k < 144; ++k) a += emb[r][k] * fc1_w[o * 144 + k];
    f1v[r][o] = eluf(a);
  }
  __syncthreads();

  // ---- fc2: 48 -> 20 ----
  if (t < BB * 20) {
    const int r = t / 20, o = t - (t / 20) * 20;
    float a = fc2_b[o];
#pragma unroll
    for (int j = 0; j < 48; ++j) a += f1v[r][j] * fc2_w[o * 48 + j];
    out[(b0 + r) * 20 + o] = a;
  }
}

extern "C" void kernel_launch(void* const* d_in, const int* in_sizes, int n_in,
                              void* d_out, int out_size, void* d_ws, size_t ws_size,
                              hipStream_t stream) {
  const float* x       = (const float*)d_in[0];
  const float* wm_di   = (const float*)d_in[1];
  const float* b_di    = (const float*)d_in[2];
  const float* fcw_di  = (const float*)d_in[3];
  const float* fcb_di  = (const float*)d_in[4];
  const float* wm_ndi  = (const float*)d_in[5];
  const float* b_ndi   = (const float*)d_in[6];
  const float* fcw_ndi = (const float*)d_in[7];
  const float* fcb_ndi = (const float*)d_in[8];
  const float* wm_dd   = (const float*)d_in[9];
  const float* b_dd    = (const float*)d_in[10];
  const float* fcw_dd  = (const float*)d_in[11];
  const float* fcb_dd  = (const float*)d_in[12];
  const float* fc1_w   = (const float*)d_in[13];
  const float* fc1_b   = (const float*)d_in[14];
  const float* fc2_w   = (const float*)d_in[15];
  const float* fc2_b   = (const float*)d_in[16];
  float* out = (float*)d_out;
  float* wredT = (float*)d_ws;  // 2*4096 floats

  wred_kernel<<<32, 256, 0, stream>>>(wm_di, wm_dd, wredT);
  fused_kernel<<<256, 256, 0, stream>>>(
      x, wm_ndi, b_di, b_ndi, b_dd,
      fcw_di, fcb_di, fcw_ndi, fcb_ndi, fcw_dd, fcb_dd,
      fc1_w, fc1_b, fc2_w, fc2_b, wredT, out);
}

// Round 2
// 46.699 us; speedup vs baseline: 1.3103x; 1.3103x over previous
//
#include <hip/hip_runtime.h>
#include <math.h>

#define BB 4

__device__ __forceinline__ float eluf(float v) {
  return v > 0.f ? v : __expf(v) - 1.f;
}

__device__ __forceinline__ float dot4(float4 a, float4 b) {
  return a.x * b.x + a.y * b.y + a.z * b.z + a.w * b.w;
}

// Precompute reduced weights for the separable DI / DD pickers:
// wredT[sel][K*64+h] = sum_I wm[h,I,K] - sum_J wm[h,K,J]
__global__ void wred_kernel(const float* __restrict__ wm_di,
                            const float* __restrict__ wm_dd,
                            float* __restrict__ wredT) {
  int t = blockIdx.x * blockDim.x + threadIdx.x;  // 0..8191
  int sel = t >> 12;
  int idx = t & 4095;
  int h = idx >> 6, K = idx & 63;
  const float* w = (sel ? wm_dd : wm_di) + h * 4096;
  float cs = 0.f, rs = 0.f;
#pragma unroll 8
  for (int I = 0; I < 64; ++I) cs += w[I * 64 + K];
#pragma unroll 8
  for (int J = 0; J < 64; ++J) rs += w[K * 64 + J];
  wredT[sel * 4096 + K * 64 + h] = cs - rs;
}

__global__ __launch_bounds__(1024) void fused_kernel(
    const float* __restrict__ x,
    const float* __restrict__ wm_ndi,
    const float* __restrict__ b_di, const float* __restrict__ b_ndi,
    const float* __restrict__ b_dd,
    const float* __restrict__ fcw_di, const float* __restrict__ fcb_di,
    const float* __restrict__ fcw_ndi, const float* __restrict__ fcb_ndi,
    const float* __restrict__ fcw_dd, const float* __restrict__ fcb_dd,
    const float* __restrict__ fc1_w, const float* __restrict__ fc1_b,
    const float* __restrict__ fc2_w, const float* __restrict__ fc2_b,
    const float* __restrict__ wredT,
    float* __restrict__ out) {
  __shared__ float xs[BB][256];
  __shared__ float pxs[BB][64];
  __shared__ float pds[BB][64];
  __shared__ float pndi[BB][4096];
  __shared__ float hh[3][BB][64];   // elu'd head activations per picker
  __shared__ float emb[BB][144];
  __shared__ float f1v[BB][48];

  const int t = threadIdx.x;
  const int b0 = blockIdx.x * BB;

  // ---- load x rows: 1024 threads = 4 rows x 256 cols ----
  {
    const int r = t >> 8, c = t & 255;
    xs[r][c] = x[(b0 + r) * 256 + c];
  }
  __syncthreads();

  // ---- pooled x and pooled (telescoped) diff: t<256, r=t>>6 lane m=t&63 ----
  // pds[r][m] = 0.25*(sms[4m+3] - sms[4m-1]) ; sms[-1] -> x[0]
  if (t < 256) {
    const int r = t >> 6, m = t & 63;
    const float* __restrict__ xr = xs[r];
    const int b4 = 4 * m;
    pxs[r][m] = 0.25f * (xr[b4] + xr[b4 + 1] + xr[b4 + 2] + xr[b4 + 3]);
    const int i3 = min(b4 + 4, 255), i4 = min(b4 + 5, 255);
    const float smv = 0.2f * (xr[b4 + 1] + xr[b4 + 2] + xr[b4 + 3] + xr[i3] + xr[i4]);
    float prev = __shfl_up(smv, 1, 64);
    if (m == 0) prev = xr[0];
    pds[r][m] = 0.25f * (smv - prev);
  }

  // ---- pooled NDI: p[I,J] = 1/16 sum_{4x4} (xj-xi)/(xj+xi+1e-5) ----
  for (int cc = t; cc < BB * 4096; cc += 1024) {
    const int r = cc >> 12;
    const int ij = cc & 4095;
    const int I = ij >> 6, J = ij & 63;
    const float4 xiv = *(const float4*)&xs[r][I << 2];
    const float4 xjv = *(const float4*)&xs[r][J << 2];
    const float xi_a[4] = {xiv.x, xiv.y, xiv.z, xiv.w};
    const float xj_a[4] = {xjv.x, xjv.y, xjv.z, xjv.w};
    float s = 0.f;
#pragma unroll
    for (int a = 0; a < 4; ++a) {
#pragma unroll
      for (int c = 0; c < 4; ++c) {
        const float num = xj_a[c] - xi_a[a];
        const float den = xj_a[c] + xi_a[a] + 1e-5f;
        s += num * __builtin_amdgcn_rcpf(den);
      }
    }
    pndi[r][ij] = s * 0.0625f;
  }
  __syncthreads();

  // ---- NDI einsum: 16 waves, wave w owns heads 4w..4w+3 (4-head register
  //      blocking: pndi read from LDS ONCE per head group) ----
  {
    const int wave = t >> 6, lane = t & 63;
    const int h0 = wave * 4;
    const float4* __restrict__ w0 = (const float4*)(wm_ndi + (h0 + 0) * 4096);
    const float4* __restrict__ w1 = (const float4*)(wm_ndi + (h0 + 1) * 4096);
    const float4* __restrict__ w2 = (const float4*)(wm_ndi + (h0 + 2) * 4096);
    const float4* __restrict__ w3 = (const float4*)(wm_ndi + (h0 + 3) * 4096);
    float acc[4][4];  // [row][head-in-group]
#pragma unroll
    for (int r = 0; r < 4; ++r)
#pragma unroll
      for (int g = 0; g < 4; ++g) acc[r][g] = 0.f;
#pragma unroll 4
    for (int k = 0; k < 16; ++k) {
      const int e = k * 64 + lane;  // float4 index into 4096-float row
      const float4 wv0 = w0[e], wv1 = w1[e], wv2 = w2[e], wv3 = w3[e];
      const float4 p0 = *(const float4*)&pndi[0][e << 2];
      const float4 p1 = *(const float4*)&pndi[1][e << 2];
      const float4 p2 = *(const float4*)&pndi[2][e << 2];
      const float4 p3 = *(const float4*)&pndi[3][e << 2];
      acc[0][0] += dot4(wv0, p0); acc[0][1] += dot4(wv1, p0);
      acc[0][2] += dot4(wv2, p0); acc[0][3] += dot4(wv3, p0);
      acc[1][0] += dot4(wv0, p1); acc[1][1] += dot4(wv1, p1);
      acc[1][2] += dot4(wv2, p1); acc[1][3] += dot4(wv3, p1);
      acc[2][0] += dot4(wv0, p2); acc[2][1] += dot4(wv1, p2);
      acc[2][2] += dot4(wv2, p2); acc[2][3] += dot4(wv3, p2);
      acc[3][0] += dot4(wv0, p3); acc[3][1] += dot4(wv1, p3);
      acc[3][2] += dot4(wv2, p3); acc[3][3] += dot4(wv3, p3);
    }
#pragma unroll
    for (int off = 32; off; off >>= 1) {
#pragma unroll
      for (int r = 0; r < 4; ++r)
#pragma unroll
        for (int g = 0; g < 4; ++g)
          acc[r][g] += __shfl_xor(acc[r][g], off, 64);
    }
    if (lane < 16) {
      const int r = lane >> 2, g = lane & 3;
      hh[1][r][h0 + g] = eluf(acc[r][g] + b_ndi[h0 + g]);
    }
  }

  // ---- DI / DD head projections via reduced weights (separable pooling) ----
  // runs in same barrier interval as einsum tail; uses pxs/pds (ready since
  // last __syncthreads) and writes disjoint hh planes.
  if (t < 256) {
    const int r = t >> 6, h = t & 63;
    float adi = b_di[h], add_ = b_dd[h];
#pragma unroll 8
    for (int K = 0; K < 64; ++K) {
      adi  += pxs[r][K] * wredT[K * 64 + h];
      add_ += pds[r][K] * wredT[4096 + K * 64 + h];
    }
    hh[0][r][h] = eluf(adi);
    hh[2][r][h] = eluf(add_);
  }
  __syncthreads();

  // ---- per-picker fc: HEAD(64) -> EMB(48), writes concatenated emb[144] ----
  if (t < BB * 144) {
    const int r = t / 144;
    const int k = t - r * 144;
    const int pick = k / 48;
    const int e = k - pick * 48;
    const float* __restrict__ fw = (pick == 0) ? fcw_di : (pick == 1) ? fcw_ndi : fcw_dd;
    const float* __restrict__ fb = (pick == 0) ? fcb_di : (pick == 1) ? fcb_ndi : fcb_dd;
    float a = fb[e];
#pragma unroll 8
    for (int hq = 0; hq < 64; ++hq) a += hh[pick][r][hq] * fw[e * 64 + hq];
    emb[r][k] = eluf(a);
  }
  __syncthreads();

  // ---- fc1: 144 -> 48, elu ----
  if (t < BB * 48) {
    const int r = t / 48, o = t - (t / 48) * 48;
    float a = fc1_b[o];
#pragma unroll 8
    for (int k = 0; k < 144; ++k) a += emb[r][k] * fc1_w[o * 144 + k];
    f1v[r][o] = eluf(a);
  }
  __syncthreads();

  // ---- fc2: 48 -> 20 ----
  if (t < BB * 20) {
    const int r = t / 20, o = t - (t / 20) * 20;
    float a = fc2_b[o];
#pragma unroll
    for (int j = 0; j < 48; ++j) a += f1v[r][j] * fc2_w[o * 48 + j];
    out[(b0 + r) * 20 + o] = a;
  }
}

extern "C" void kernel_launch(void* const* d_in, const int* in_sizes, int n_in,
                              void* d_out, int out_size, void* d_ws, size_t ws_size,
                              hipStream_t stream) {
  const float* x       = (const float*)d_in[0];
  const float* wm_di   = (const float*)d_in[1];
  const float* b_di    = (const float*)d_in[2];
  const float* fcw_di  = (const float*)d_in[3];
  const float* fcb_di  = (const float*)d_in[4];
  const float* wm_ndi  = (const float*)d_in[5];
  const float* b_ndi   = (const float*)d_in[6];
  const float* fcw_ndi = (const float*)d_in[7];
  const float* fcb_ndi = (const float*)d_in[8];
  const float* wm_dd   = (const float*)d_in[9];
  const float* b_dd    = (const float*)d_in[10];
  const float* fcw_dd  = (const float*)d_in[11];
  const float* fcb_dd  = (const float*)d_in[12];
  const float* fc1_w   = (const float*)d_in[13];
  const float* fc1_b   = (const float*)d_in[14];
  const float* fc2_w   = (const float*)d_in[15];
  const float* fc2_b   = (const float*)d_in[16];
  float* out = (float*)d_out;
  float* wredT = (float*)d_ws;  // 2*4096 floats

  wred_kernel<<<32, 256, 0, stream>>>(wm_di, wm_dd, wredT);
  fused_kernel<<<256, 1024, 0, stream>>>(
      x, wm_ndi, b_di, b_ndi, b_dd,
      fcw_di, fcb_di, fcw_ndi, fcb_ndi, fcw_dd, fcb_dd,
      fc1_w, fc1_b, fc2_w, fc2_b, wredT, out);
}

// Round 3
// 32.336 us; speedup vs baseline: 1.8922x; 1.4442x over previous
//
#include <hip/hip_runtime.h>
#include <math.h>

#define BB 4

__device__ __forceinline__ float eluf(float v) {
  return v > 0.f ? v : __expf(v) - 1.f;
}

__device__ __forceinline__ float dot4(float4 a, float4 b) {
  return a.x * b.x + a.y * b.y + a.z * b.z + a.w * b.w;
}

// prep kernel:
//  blocks 0..31   : wredT[sel][K][h] = colsum - rowsum of wm_di / wm_dd (separable DI/DD)
//  blocks 32..543 : wmA[h][e] = 0.0625*(wm_ndi[h,I,J] - wm_ndi[h,J,I]) on the
//                   antisymmetric rectangle mapping e -> (I = e>>5, J = (I+1+(e&31))&63),
//                   zeroed on the 32 duplicate d=32 columns (e&31==31 && I>=32).
__global__ void prep_kernel(const float* __restrict__ wm_di,
                            const float* __restrict__ wm_ndi,
                            const float* __restrict__ wm_dd,
                            float* __restrict__ ws) {
  float* wredT = ws;         // 2*4096 floats
  float* wmA   = ws + 8192;  // 64*2048 floats
  if (blockIdx.x < 32) {
    int t = blockIdx.x * 256 + threadIdx.x;  // 0..8191
    int sel = t >> 12, idx = t & 4095;
    int h = idx >> 6, K = idx & 63;
    const float* w = (sel ? wm_dd : wm_di) + h * 4096;
    float cs = 0.f, rs = 0.f;
#pragma unroll 8
    for (int I = 0; I < 64; ++I) cs += w[I * 64 + K];
#pragma unroll 8
    for (int J = 0; J < 64; ++J) rs += w[K * 64 + J];
    wredT[sel * 4096 + K * 64 + h] = cs - rs;
  } else {
    int gid = (blockIdx.x - 32) * 256 + threadIdx.x;  // 0..131071
    int h = gid >> 11, e = gid & 2047;
    int I = e >> 5, tt = e & 31;
    int J = (I + 1 + tt) & 63;
    float v = 0.f;
    if (!(tt == 31 && I >= 32)) {
      const float* w = wm_ndi + h * 4096;
      v = 0.0625f * (w[I * 64 + J] - w[J * 64 + I]);
    }
    wmA[h * 2048 + e] = v;
  }
}

__global__ __launch_bounds__(1024) void fused_kernel(
    const float* __restrict__ x,
    const float* __restrict__ b_di, const float* __restrict__ b_ndi,
    const float* __restrict__ b_dd,
    const float* __restrict__ fcw_di, const float* __restrict__ fcb_di,
    const float* __restrict__ fcw_ndi, const float* __restrict__ fcb_ndi,
    const float* __restrict__ fcw_dd, const float* __restrict__ fcb_dd,
    const float* __restrict__ fc1_w, const float* __restrict__ fc1_b,
    const float* __restrict__ fc2_w, const float* __restrict__ fc2_b,
    const float* __restrict__ ws,
    float* __restrict__ out) {
  const float* __restrict__ wredT = ws;         // [2][64][64]
  const float* __restrict__ wmA   = ws + 8192;  // [64][2048]

  __shared__ float xs[BB][256];
  __shared__ float pxs[BB][64];
  __shared__ float pds[BB][64];
  __shared__ float pnA[BB][2048];   // antisym rectangle of pooled NDI
  __shared__ float hh[3][BB][64];
  __shared__ float emb[BB][144];
  __shared__ float f1v[BB][48];

  const int t = threadIdx.x;
  const int b0 = blockIdx.x * BB;

  // ---- load x rows: 1024 threads = 4 rows x 256 cols ----
  {
    const int r = t >> 8, c = t & 255;
    xs[r][c] = x[(b0 + r) * 256 + c];
  }
  __syncthreads();

  // ---- pooled x and pooled (telescoped) diff ----
  if (t < 256) {
    const int r = t >> 6, m = t & 63;
    const float* __restrict__ xr = xs[r];
    const int b4 = 4 * m;
    pxs[r][m] = 0.25f * (xr[b4] + xr[b4 + 1] + xr[b4 + 2] + xr[b4 + 3]);
    const int i3 = min(b4 + 4, 255), i4 = min(b4 + 5, 255);
    const float smv = 0.2f * (xr[b4 + 1] + xr[b4 + 2] + xr[b4 + 3] + xr[i3] + xr[i4]);
    float prev = __shfl_up(smv, 1, 64);
    if (m == 0) prev = xr[0];
    pds[r][m] = 0.25f * (smv - prev);
  }

  // ---- pooled NDI, antisymmetric half only: 8 entries/thread ----
  // e -> (I = e>>5, J = (I+1+(e&31))&63); duplicate d=32 entries computed
  // anyway (their wmA column is zero, value irrelevant but finite).
  for (int cc = t; cc < BB * 2048; cc += 1024) {
    const int r = cc >> 11;
    const int e = cc & 2047;
    const int I = e >> 5;
    const int J = (I + 1 + (e & 31)) & 63;
    const float4 xiv = *(const float4*)&xs[r][I << 2];
    const float4 xjv = *(const float4*)&xs[r][J << 2];
    const float xi_a[4] = {xiv.x, xiv.y, xiv.z, xiv.w};
    const float xj_a[4] = {xjv.x + 1e-5f, xjv.y + 1e-5f, xjv.z + 1e-5f, xjv.w + 1e-5f};
    const float xn_a[4] = {xjv.x, xjv.y, xjv.z, xjv.w};
    float s = 0.f;
#pragma unroll
    for (int a = 0; a < 4; ++a) {
#pragma unroll
      for (int c = 0; c < 4; ++c) {
        const float num = xn_a[c] - xi_a[a];
        const float den = xj_a[c] + xi_a[a];
        s += num * __builtin_amdgcn_rcpf(den);
      }
    }
    pnA[r][e] = s;  // 1/16 folded into wmA
  }
  __syncthreads();

  // ---- NDI einsum over antisym half: 16 waves x 4 heads, 8 k-iters ----
  {
    const int wave = t >> 6, lane = t & 63;
    const int h0 = wave * 4;
    const float4* __restrict__ w0 = (const float4*)(wmA + (h0 + 0) * 2048);
    const float4* __restrict__ w1 = (const float4*)(wmA + (h0 + 1) * 2048);
    const float4* __restrict__ w2 = (const float4*)(wmA + (h0 + 2) * 2048);
    const float4* __restrict__ w3 = (const float4*)(wmA + (h0 + 3) * 2048);
    float acc[16];  // q = r*4 + g
#pragma unroll
    for (int q = 0; q < 16; ++q) acc[q] = 0.f;
#pragma unroll
    for (int k = 0; k < 8; ++k) {
      const int e4 = k * 64 + lane;
      const float4 wv0 = w0[e4], wv1 = w1[e4], wv2 = w2[e4], wv3 = w3[e4];
      const float4 p0 = *(const float4*)&pnA[0][e4 << 2];
      const float4 p1 = *(const float4*)&pnA[1][e4 << 2];
      const float4 p2 = *(const float4*)&pnA[2][e4 << 2];
      const float4 p3 = *(const float4*)&pnA[3][e4 << 2];
      acc[0]  += dot4(wv0, p0); acc[1]  += dot4(wv1, p0);
      acc[2]  += dot4(wv2, p0); acc[3]  += dot4(wv3, p0);
      acc[4]  += dot4(wv0, p1); acc[5]  += dot4(wv1, p1);
      acc[6]  += dot4(wv2, p1); acc[7]  += dot4(wv3, p1);
      acc[8]  += dot4(wv0, p2); acc[9]  += dot4(wv1, p2);
      acc[10] += dot4(wv2, p2); acc[11] += dot4(wv3, p2);
      acc[12] += dot4(wv0, p3); acc[13] += dot4(wv1, p3);
      acc[14] += dot4(wv2, p3); acc[15] += dot4(wv3, p3);
    }
    // multi-value butterfly reduce: after 4 merge levels lane l holds the
    // 16-lane-group partial of acc[l&15]; 2 more butterflies -> full sum.
#pragma unroll
    for (int i = 0; i < 8; ++i) {
      const float u = acc[2 * i], v = acc[2 * i + 1];
      const float sel = (lane & 1) ? u : v;
      const float sh = __shfl_xor(sel, 1, 64);
      acc[i] = ((lane & 1) ? v : u) + sh;
    }
#pragma unroll
    for (int i = 0; i < 4; ++i) {
      const float u = acc[2 * i], v = acc[2 * i + 1];
      const float sel = (lane & 2) ? u : v;
      const float sh = __shfl_xor(sel, 2, 64);
      acc[i] = ((lane & 2) ? v : u) + sh;
    }
#pragma unroll
    for (int i = 0; i < 2; ++i) {
      const float u = acc[2 * i], v = acc[2 * i + 1];
      const float sel = (lane & 4) ? u : v;
      const float sh = __shfl_xor(sel, 4, 64);
      acc[i] = ((lane & 4) ? v : u) + sh;
    }
    {
      const float u = acc[0], v = acc[1];
      const float sel = (lane & 8) ? u : v;
      const float sh = __shfl_xor(sel, 8, 64);
      acc[0] = ((lane & 8) ? v : u) + sh;
    }
    float rsum = acc[0];
    rsum += __shfl_xor(rsum, 16, 64);
    rsum += __shfl_xor(rsum, 32, 64);
    if (lane < 16) {
      const int rr = lane >> 2, g = lane & 3;
      hh[1][rr][h0 + g] = eluf(rsum + b_ndi[h0 + g]);
    }
  }

  // ---- DI / DD head projections via reduced weights (same barrier interval) ----
  if (t < 256) {
    const int r = t >> 6, h = t & 63;
    float adi = b_di[h], add_ = b_dd[h];
#pragma unroll 8
    for (int K = 0; K < 64; ++K) {
      adi  += pxs[r][K] * wredT[K * 64 + h];
      add_ += pds[r][K] * wredT[4096 + K * 64 + h];
    }
    hh[0][r][h] = eluf(adi);
    hh[2][r][h] = eluf(add_);
  }
  __syncthreads();

  // ---- per-picker fc: HEAD(64) -> EMB(48) ----
  if (t < BB * 144) {
    const int r = t / 144;
    const int k = t - r * 144;
    const int pick = k / 48;
    const int e = k - pick * 48;
    const float* __restrict__ fw = (pick == 0) ? fcw_di : (pick == 1) ? fcw_ndi : fcw_dd;
    const float* __restrict__ fb = (pick == 0) ? fcb_di : (pick == 1) ? fcb_ndi : fcb_dd;
    float a = fb[e];
#pragma unroll 8
    for (int hq = 0; hq < 64; ++hq) a += hh[pick][r][hq] * fw[e * 64 + hq];
    emb[r][k] = eluf(a);
  }
  __syncthreads();

  // ---- fc1: 144 -> 48, elu ----
  if (t < BB * 48) {
    const int r = t / 48, o = t - (t / 48) * 48;
    float a = fc1_b[o];
#pragma unroll 8
    for (int k = 0; k < 144; ++k) a += emb[r][k] * fc1_w[o * 144 + k];
    f1v[r][o] = eluf(a);
  }
  __syncthreads();

  // ---- fc2: 48 -> 20 ----
  if (t < BB * 20) {
    const int r = t / 20, o = t - (t / 20) * 20;
    float a = fc2_b[o];
#pragma unroll
    for (int j = 0; j < 48; ++j) a += f1v[r][j] * fc2_w[o * 48 + j];
    out[(b0 + r) * 20 + o] = a;
  }
}

extern "C" void kernel_launch(void* const* d_in, const int* in_sizes, int n_in,
                              void* d_out, int out_size, void* d_ws, size_t ws_size,
                              hipStream_t stream) {
  const float* x       = (const float*)d_in[0];
  const float* wm_di   = (const float*)d_in[1];
  const float* b_di    = (const float*)d_in[2];
  const float* fcw_di  = (const float*)d_in[3];
  const float* fcb_di  = (const float*)d_in[4];
  const float* wm_ndi  = (const float*)d_in[5];
  const float* b_ndi   = (const float*)d_in[6];
  const float* fcw_ndi = (const float*)d_in[7];
  const float* fcb_ndi = (const float*)d_in[8];
  const float* wm_dd   = (const float*)d_in[9];
  const float* b_dd    = (const float*)d_in[10];
  const float* fcw_dd  = (const float*)d_in[11];
  const float* fcb_dd  = (const float*)d_in[12];
  const float* fc1_w   = (const float*)d_in[13];
  const float* fc1_b   = (const float*)d_in[14];
  const float* fc2_w   = (const float*)d_in[15];
  const float* fc2_b   = (const float*)d_in[16];
  float* out = (float*)d_out;
  float* ws  = (float*)d_ws;  // wredT: 8192 floats, wmA: 131072 floats (544 KB)

  prep_kernel<<<544, 256, 0, stream>>>(wm_di, wm_ndi, wm_dd, ws);
  fused_kernel<<<256, 1024, 0, stream>>>(
      x, b_di, b_ndi, b_dd,
      fcw_di, fcb_di, fcw_ndi, fcb_ndi, fcw_dd, fcb_dd,
      fc1_w, fc1_b, fc2_w, fc2_b, ws, out);
}